// Round 12
// baseline (166.986 us; speedup 1.0000x reference)
//
#include <hip/hip_runtime.h>
#include <stdint.h>

typedef __bf16 bf16x8 __attribute__((ext_vector_type(8)));
typedef float f32x4 __attribute__((ext_vector_type(4)));
typedef __attribute__((address_space(3))) uint32_t as3u32;
typedef const __attribute__((address_space(1))) uint32_t as1u32;

#define B_TOT 8192
#define DD 128
#define OUT_TOT 67108864UL
#define OUT_AVG 67117056UL

__device__ inline unsigned short f2bf(float x){
  union { float f; uint32_t u; } v; v.f = x;
  return (unsigned short)((v.u + 0x7fffu + ((v.u >> 16) & 1u)) >> 16);
}

// ------- phase 1: gather + normalize + h + pos; one wave per sample ------------
__global__ __launch_bounds__(256) void k_feat(const float* __restrict__ x1,
    const float* __restrict__ x2, const int* __restrict__ i1a, const int* __restrict__ i2a,
    unsigned short* __restrict__ f1b, unsigned short* __restrict__ f2b,
    unsigned short* __restrict__ hb, float* __restrict__ posw, float* __restrict__ out){
  int tid = threadIdx.x;
  int gid = blockIdx.x * 256 + tid;
  if (gid <= 8192) out[OUT_TOT + gid] = 0.f;   // zero tot accum + avg slot
  int w = tid >> 6, l = tid & 63;
  int b = blockIdx.x * 4 + w;                  // grid 2048 -> b 0..8191
  const float2* r1 = (const float2*)(x1 + (size_t)i1a[b] * DD);
  const float2* r2 = (const float2*)(x2 + (size_t)i2a[b] * DD);
  float2 v1 = r1[l], v2 = r2[l];
  float s1 = v1.x * v1.x + v1.y * v1.y;
  float s2 = v2.x * v2.x + v2.y * v2.y;
  #pragma unroll
  for (int o = 32; o; o >>= 1){ s1 += __shfl_xor(s1, o); s2 += __shfl_xor(s2, o); }
  float inv1 = 1.f / fmaxf(sqrtf(s1), 1e-12f);
  float inv2 = 1.f / fmaxf(sqrtf(s2), 1e-12f);
  float f1x = v1.x * inv1, f1y = v1.y * inv1;
  float f2x = v2.x * inv2, f2y = v2.y * inv2;
  float hx = f1x * f2x, hy = f1y * f2y;
  float ps = hx + hy;
  #pragma unroll
  for (int o = 32; o; o >>= 1) ps += __shfl_xor(ps, o);
  unsigned int u1 = (unsigned int)f2bf(f1x) | ((unsigned int)f2bf(f1y) << 16);
  unsigned int u2 = (unsigned int)f2bf(f2x) | ((unsigned int)f2bf(f2y) << 16);
  unsigned int uh = (unsigned int)f2bf(hx)  | ((unsigned int)f2bf(hy)  << 16);
  ((unsigned int*)f1b)[b * 64 + l] = u1;
  ((unsigned int*)f2b)[b * 64 + l] = u2;
  ((unsigned int*)hb)[b * 64 + l]  = uh;
  if (l == 0) posw[b] = ps;
}

// ---------------- shared staging (128x128 bf16 tile, XOR-swizzled) ----------------
__device__ inline void stage_tile(const unsigned short* g, unsigned short* s){
  int tid = threadIdx.x;
  #pragma unroll
  for (int it = 0; it < 8; ++it){
    int c = tid + it * 256;          // 2048 chunks of 16B
    int row = c >> 4, cc = c & 15;
    int src = (row << 4) + (cc ^ (row & 7));
    __builtin_amdgcn_global_load_lds((as1u32*)(g + src * 8),
                                     (as3u32*)(s + c * 8), 16, 0, 0);
  }
}

// A-frag: row = lane&15, k = 8*(lane>>4)+e. C/D: col = lane&15, row=(lane>>4)*4+reg.
__device__ inline void mfma_tile(const unsigned short* As, const unsigned short* Bs,
                                 f32x4 acc[4][4]){
  int tid = threadIdx.x;
  int w = tid >> 6, l = tid & 63;
  int wr = (w >> 1) * 64, wc = (w & 1) * 64;
  int lo = l & 15, hi = l >> 4;
  f32x4 zero = {0.f, 0.f, 0.f, 0.f};
  #pragma unroll
  for (int m = 0; m < 4; ++m)
    #pragma unroll
    for (int n = 0; n < 4; ++n) acc[m][n] = zero;
  #pragma unroll
  for (int kk = 0; kk < 4; ++kk){
    bf16x8 af[4], bfv[4];
    #pragma unroll
    for (int m = 0; m < 4; ++m){
      int row = wr + m * 16 + lo;
      af[m] = *(const bf16x8*)(As + row * 128 + ((kk * 4 + hi) ^ (row & 7)) * 8);
    }
    #pragma unroll
    for (int n = 0; n < 4; ++n){
      int row = wc + n * 16 + lo;
      bfv[n] = *(const bf16x8*)(Bs + row * 128 + ((kk * 4 + hi) ^ (row & 7)) * 8);
    }
    #pragma unroll
    for (int m = 0; m < 4; ++m)
      #pragma unroll
      for (int n = 0; n < 4; ++n)
        acc[m][n] = __builtin_amdgcn_mfma_f32_16x16x32_bf16(af[m], bfv[n], acc[m][n], 0, 0, 0);
  }
}

// ---------------- phase 2: lin1 + leaky + lin2 + sigmoid -> rT, temp-mean -------
__global__ __launch_bounds__(256) void k_lin(const unsigned short* __restrict__ hb,
    const float* __restrict__ W1, const float* __restrict__ b1,
    const float* __restrict__ W2, const float* __restrict__ b2,
    float* __restrict__ rTw, float* __restrict__ out){
  __shared__ __align__(16) unsigned short As[16384];
  __shared__ __align__(16) unsigned short Bs[16384];
  __shared__ float zpart[2][128];
  __shared__ float s4[4];
  int i0 = blockIdx.x * 128;
  int tid = threadIdx.x;
  stage_tile(hb + (size_t)i0 * 128, As);
  #pragma unroll
  for (int it = 0; it < 8; ++it){
    int c = tid + it * 256;
    int row = c >> 4, cc = c & 15;
    int src = (row << 4) + (cc ^ (row & 7));
    const float4* g4 = (const float4*)(W1 + src * 8);
    float4 a = g4[0], b = g4[1];
    unsigned short t8[8];
    t8[0] = f2bf(a.x); t8[1] = f2bf(a.y); t8[2] = f2bf(a.z); t8[3] = f2bf(a.w);
    t8[4] = f2bf(b.x); t8[5] = f2bf(b.y); t8[6] = f2bf(b.z); t8[7] = f2bf(b.w);
    *(uint4*)(Bs + c * 8) = *(uint4*)t8;
  }
  asm volatile("s_waitcnt vmcnt(0)" ::: "memory");
  __syncthreads();
  f32x4 acc[4][4];
  mfma_tile(As, Bs, acc);
  int w = tid >> 6, l = tid & 63;
  int wrb = (w >> 1) * 64, wcb = (w & 1) * 64, lo = l & 15, hi = l >> 4;
  float w2v[4], b1v[4];
  #pragma unroll
  for (int n = 0; n < 4; ++n){ int col = wcb + n * 16 + lo; w2v[n] = W2[col]; b1v[n] = b1[col]; }
  #pragma unroll
  for (int m = 0; m < 4; ++m){
    #pragma unroll
    for (int q = 0; q < 4; ++q){
      float p = 0.f;
      #pragma unroll
      for (int n = 0; n < 4; ++n){
        float hv = acc[m][n][q] + b1v[n];
        hv = hv >= 0.f ? hv : 0.2f * hv;   // leaky_relu(0.2)
        p += hv * w2v[n];
      }
      p += __shfl_xor(p, 1); p += __shfl_xor(p, 2);
      p += __shfl_xor(p, 4); p += __shfl_xor(p, 8);
      if (lo == 0) zpart[w & 1][wrb + m * 16 + hi * 4 + q] = p;
    }
  }
  __syncthreads();
  float Tloc = 0.f;
  if (tid < 128){
    float z = zpart[0][tid] + zpart[1][tid] + b2[0];
    float s = 1.f / (1.f + __expf(-z));
    float T = 0.95f * (1.f - s) + 0.05f;
    rTw[i0 + tid] = 1.f / T;
    Tloc = T;
  }
  float v = Tloc;
  #pragma unroll
  for (int o = 32; o; o >>= 1) v += __shfl_xor(v, o);
  if ((tid & 63) == 0) s4[tid >> 6] = v;
  __syncthreads();
  if (tid == 0) atomicAdd(out + OUT_AVG, (s4[0] + s4[1] + s4[2] + s4[3]) * (1.0f / 8192.0f));
}

// ------- phase 3: block-specialized fused kernel (R10, best known) --------------
__global__ __launch_bounds__(256) void k_main(const unsigned short* __restrict__ f1b,
    const unsigned short* __restrict__ f2b, const float* __restrict__ rTw,
    const float* __restrict__ posw, float* __restrict__ out){
  __shared__ __align__(16) unsigned short Buf[16384];   // 32 KB (GEMM role only)
  __shared__ __align__(16) float rS[128];
  int bid = blockIdx.x;
  int tid = threadIdx.x;
  if (bid % 5 == 2){
    // ---------------- GEMM role ----------------
    int g = bid / 5;
    int s = (g & 7) * 64 + (g >> 3);    // XCD-chunked, bijective (512 % 8 == 0)
    int rt = s & 63, ctg = s >> 6;
    int w = tid >> 6, l = tid & 63;
    int wr = (w >> 1) * 64, wc = (w & 1) * 64;
    int lo = l & 15, hi = l >> 4;
    stage_tile(f1b + (size_t)rt * 16384, Buf);
    if (tid < 32)
      __builtin_amdgcn_global_load_lds((as1u32*)(rTw + rt * 128 + tid * 4),
                                       (as3u32*)(rS + tid * 4), 16, 0, 0);
    asm volatile("s_waitcnt vmcnt(0)" ::: "memory");
    __builtin_amdgcn_s_barrier();
    bf16x8 af[4][4];                 // A fragments in registers
    #pragma unroll
    for (int kk = 0; kk < 4; ++kk)
      #pragma unroll
      for (int m = 0; m < 4; ++m){
        int row = wr + m * 16 + lo;
        af[kk][m] = *(const bf16x8*)(Buf + row * 128 + ((kk * 4 + hi) ^ (row & 7)) * 8);
      }
    asm volatile("s_waitcnt lgkmcnt(0)" ::: "memory");
    __builtin_amdgcn_s_barrier();    // Buf free for B staging
    stage_tile(f2b + (size_t)(ctg * 8) * 16384, Buf);
    asm volatile("s_waitcnt vmcnt(0)" ::: "memory");
    __builtin_amdgcn_s_barrier();    // B(0) ready
    float pacc[4][4] = {{0.f,0.f,0.f,0.f},{0.f,0.f,0.f,0.f},{0.f,0.f,0.f,0.f},{0.f,0.f,0.f,0.f}};
    #pragma unroll 1
    for (int c8 = 0; c8 < 8; ++c8){
      int ct = ctg * 8 + c8;
      f32x4 acc[4][4];
      f32x4 zero = {0.f,0.f,0.f,0.f};
      #pragma unroll
      for (int m = 0; m < 4; ++m)
        #pragma unroll
        for (int n = 0; n < 4; ++n) acc[m][n] = zero;
      #pragma unroll
      for (int kk = 0; kk < 4; ++kk){
        bf16x8 bfv[4];
        #pragma unroll
        for (int n = 0; n < 4; ++n){
          int row = wc + n * 16 + lo;
          bfv[n] = *(const bf16x8*)(Buf + row * 128 + ((kk * 4 + hi) ^ (row & 7)) * 8);
        }
        #pragma unroll
        for (int m = 0; m < 4; ++m)
          #pragma unroll
          for (int n = 0; n < 4; ++n)
            acc[m][n] = __builtin_amdgcn_mfma_f32_16x16x32_bf16(af[kk][m], bfv[n], acc[m][n], 0, 0, 0);
      }
      asm volatile("s_waitcnt lgkmcnt(0)" ::: "memory");
      __builtin_amdgcn_s_barrier();        // all waves done reading Buf
      if (c8 < 7) stage_tile(f2b + (size_t)(ct + 1) * 16384, Buf);   // prefetch next
      #pragma unroll
      for (int m = 0; m < 4; ++m)
        #pragma unroll
        for (int q = 0; q < 4; ++q){
          float r = rS[wr + m * 16 + hi * 4 + q];
          pacc[m][q] += __expf(acc[m][0][q] * r) + __expf(acc[m][1][q] * r)
                      + __expf(acc[m][2][q] * r) + __expf(acc[m][3][q] * r);
        }
      if (c8 < 7){
        asm volatile("s_waitcnt vmcnt(0)" ::: "memory");
        __builtin_amdgcn_s_barrier();      // B(c8+1) ready
      }
    }
    #pragma unroll
    for (int m = 0; m < 4; ++m)
      #pragma unroll
      for (int q = 0; q < 4; ++q){
        float p = pacc[m][q];
        p += __shfl_xor(p, 1); p += __shfl_xor(p, 2);
        p += __shfl_xor(p, 4); p += __shfl_xor(p, 8);
        if (lo == 0) atomicAdd(out + OUT_TOT + rt * 128 + wr + m * 16 + hi * 4 + q, p);
      }
  } else {
    // ---------------- writer role ----------------
    int wid = bid - bid / 5 - ((bid % 5) > 2 ? 1 : 0);   // 0..2047, bijective
    int r0 = wid * 4;
    f32x4 p[8];
    #pragma unroll
    for (int c = 0; c < 8; ++c) p[c] = *(const f32x4*)(posw + (c * 256 + tid) * 4);
    float4 rr4 = *(const float4*)(rTw + r0);
    float rr[4] = {rr4.x, rr4.y, rr4.z, rr4.w};
    #pragma unroll
    for (int r = 0; r < 4; ++r){
      float* ob = out + (size_t)(r0 + r) * B_TOT;
      #pragma unroll
      for (int c = 0; c < 8; ++c){
        f32x4 e;
        e.x = __expf(p[c].x * rr[r]); e.y = __expf(p[c].y * rr[r]);
        e.z = __expf(p[c].z * rr[r]); e.w = __expf(p[c].w * rr[r]);
        *(f32x4*)(ob + (c * 256 + tid) * 4) = e;
      }
    }
  }
}

// ------- PROBE A: constant writer, exact shape of best writer, no reads/exp ----
__global__ __launch_bounds__(256) void k_fillp(float* __restrict__ out){
  int tid = threadIdx.x;
  size_t base = (size_t)blockIdx.x * 32768;   // 4 rows x 8192 floats
  f32x4 v = {1.f, 1.f, 1.f, 1.f};
  #pragma unroll
  for (int c = 0; c < 32; ++c)
    *(f32x4*)(out + base + c * 1024 + tid * 4) = v;
}

// ------- PROBE B: R9 writer (reads + exp), overwrites probe A with real values -
__global__ __launch_bounds__(256) void k_pr(const float* __restrict__ posw,
    const float* __restrict__ rTw, float* __restrict__ out){
  int tid = threadIdx.x;
  int r0 = blockIdx.x * 4;
  f32x4 p[8];
  #pragma unroll
  for (int c = 0; c < 8; ++c) p[c] = *(const f32x4*)(posw + (c * 256 + tid) * 4);
  float4 rr4 = *(const float4*)(rTw + r0);
  float rr[4] = {rr4.x, rr4.y, rr4.z, rr4.w};
  #pragma unroll
  for (int r = 0; r < 4; ++r){
    float* ob = out + (size_t)(r0 + r) * B_TOT;
    #pragma unroll
    for (int c = 0; c < 8; ++c){
      f32x4 e;
      e.x = __expf(p[c].x * rr[r]); e.y = __expf(p[c].y * rr[r]);
      e.z = __expf(p[c].z * rr[r]); e.w = __expf(p[c].w * rr[r]);
      *(f32x4*)(ob + (c * 256 + tid) * 4) = e;
    }
  }
}

extern "C" void kernel_launch(void* const* d_in, const int* in_sizes, int n_in,
                              void* d_out, int out_size, void* d_ws, size_t ws_size,
                              hipStream_t stream){
  const float* x1 = (const float*)d_in[0];
  const float* x2 = (const float*)d_in[1];
  const int*   i1 = (const int*)d_in[2];
  const int*   i2 = (const int*)d_in[3];
  const float* W1 = (const float*)d_in[4];
  const float* b1 = (const float*)d_in[5];
  const float* W2 = (const float*)d_in[6];
  const float* b2 = (const float*)d_in[7];
  float* out = (float*)d_out;
  char* ws = (char*)d_ws;
  unsigned short* hb   = (unsigned short*)(ws);              // 2 MB
  unsigned short* f1b  = (unsigned short*)(ws + 2097152);    // 2 MB
  unsigned short* f2b  = (unsigned short*)(ws + 4194304);    // 2 MB
  float* posw  = (float*)(ws + 6291456);                     // 32 KB
  float* rTw   = (float*)(ws + 6324224);                     // 32 KB

  hipLaunchKernelGGL(k_feat,  dim3(2048), dim3(256), 0, stream, x1, x2, i1, i2, f1b, f2b, hb, posw, out);
  hipLaunchKernelGGL(k_lin,   dim3(64),   dim3(256), 0, stream, hb, W1, b1, W2, b2, rTw, out);
  hipLaunchKernelGGL(k_main,  dim3(2560), dim3(256), 0, stream, f1b, f2b, rTw, posw, out);
  // probes: A (constant fill-mimic) then B (real writer restores correct values)
  hipLaunchKernelGGL(k_fillp, dim3(2048), dim3(256), 0, stream, out);
  hipLaunchKernelGGL(k_pr,    dim3(2048), dim3(256), 0, stream, posw, rTw, out);
}

// Round 13
// 94.961 us; speedup vs baseline: 1.7585x; 1.7585x over previous
//
#include <hip/hip_runtime.h>
#include <stdint.h>

typedef __bf16 bf16x8 __attribute__((ext_vector_type(8)));
typedef float f32x4 __attribute__((ext_vector_type(4)));
typedef __attribute__((address_space(3))) uint32_t as3u32;
typedef const __attribute__((address_space(1))) uint32_t as1u32;

#define B_TOT 8192
#define DD 128
#define OUT_TOT 67108864UL
#define OUT_AVG 67117056UL

__device__ inline unsigned short f2bf(float x){
  union { float f; uint32_t u; } v; v.f = x;
  return (unsigned short)((v.u + 0x7fffu + ((v.u >> 16) & 1u)) >> 16);
}

// ------- phase 1: gather + normalize + h + pos; one wave per sample ------------
__global__ __launch_bounds__(256) void k_feat(const float* __restrict__ x1,
    const float* __restrict__ x2, const int* __restrict__ i1a, const int* __restrict__ i2a,
    unsigned short* __restrict__ f1b, unsigned short* __restrict__ f2b,
    unsigned short* __restrict__ hb, float* __restrict__ posw, float* __restrict__ out){
  int tid = threadIdx.x;
  int gid = blockIdx.x * 256 + tid;
  if (gid <= 8192) out[OUT_TOT + gid] = 0.f;   // zero tot accum + avg slot
  int w = tid >> 6, l = tid & 63;
  int b = blockIdx.x * 4 + w;                  // grid 2048 -> b 0..8191
  const float2* r1 = (const float2*)(x1 + (size_t)i1a[b] * DD);
  const float2* r2 = (const float2*)(x2 + (size_t)i2a[b] * DD);
  float2 v1 = r1[l], v2 = r2[l];
  float s1 = v1.x * v1.x + v1.y * v1.y;
  float s2 = v2.x * v2.x + v2.y * v2.y;
  #pragma unroll
  for (int o = 32; o; o >>= 1){ s1 += __shfl_xor(s1, o); s2 += __shfl_xor(s2, o); }
  float inv1 = 1.f / fmaxf(sqrtf(s1), 1e-12f);
  float inv2 = 1.f / fmaxf(sqrtf(s2), 1e-12f);
  float f1x = v1.x * inv1, f1y = v1.y * inv1;
  float f2x = v2.x * inv2, f2y = v2.y * inv2;
  float hx = f1x * f2x, hy = f1y * f2y;
  float ps = hx + hy;
  #pragma unroll
  for (int o = 32; o; o >>= 1) ps += __shfl_xor(ps, o);
  unsigned int u1 = (unsigned int)f2bf(f1x) | ((unsigned int)f2bf(f1y) << 16);
  unsigned int u2 = (unsigned int)f2bf(f2x) | ((unsigned int)f2bf(f2y) << 16);
  unsigned int uh = (unsigned int)f2bf(hx)  | ((unsigned int)f2bf(hy)  << 16);
  ((unsigned int*)f1b)[b * 64 + l] = u1;
  ((unsigned int*)f2b)[b * 64 + l] = u2;
  ((unsigned int*)hb)[b * 64 + l]  = uh;
  if (l == 0) posw[b] = ps;
}

// ---------------- shared staging (128x128 bf16 tile, XOR-swizzled) ----------------
__device__ inline void stage_tile(const unsigned short* g, unsigned short* s){
  int tid = threadIdx.x;
  #pragma unroll
  for (int it = 0; it < 8; ++it){
    int c = tid + it * 256;          // 2048 chunks of 16B
    int row = c >> 4, cc = c & 15;
    int src = (row << 4) + (cc ^ (row & 7));
    __builtin_amdgcn_global_load_lds((as1u32*)(g + src * 8),
                                     (as3u32*)(s + c * 8), 16, 0, 0);
  }
}

// A-frag: row = lane&15, k = 8*(lane>>4)+e. C/D: col = lane&15, row=(lane>>4)*4+reg.
__device__ inline void mfma_tile(const unsigned short* As, const unsigned short* Bs,
                                 f32x4 acc[4][4]){
  int tid = threadIdx.x;
  int w = tid >> 6, l = tid & 63;
  int wr = (w >> 1) * 64, wc = (w & 1) * 64;
  int lo = l & 15, hi = l >> 4;
  f32x4 zero = {0.f, 0.f, 0.f, 0.f};
  #pragma unroll
  for (int m = 0; m < 4; ++m)
    #pragma unroll
    for (int n = 0; n < 4; ++n) acc[m][n] = zero;
  #pragma unroll
  for (int kk = 0; kk < 4; ++kk){
    bf16x8 af[4], bfv[4];
    #pragma unroll
    for (int m = 0; m < 4; ++m){
      int row = wr + m * 16 + lo;
      af[m] = *(const bf16x8*)(As + row * 128 + ((kk * 4 + hi) ^ (row & 7)) * 8);
    }
    #pragma unroll
    for (int n = 0; n < 4; ++n){
      int row = wc + n * 16 + lo;
      bfv[n] = *(const bf16x8*)(Bs + row * 128 + ((kk * 4 + hi) ^ (row & 7)) * 8);
    }
    #pragma unroll
    for (int m = 0; m < 4; ++m)
      #pragma unroll
      for (int n = 0; n < 4; ++n)
        acc[m][n] = __builtin_amdgcn_mfma_f32_16x16x32_bf16(af[m], bfv[n], acc[m][n], 0, 0, 0);
  }
}

// ---------------- phase 2: lin1 + leaky + lin2 + sigmoid -> rT, temp-mean -------
__global__ __launch_bounds__(256) void k_lin(const unsigned short* __restrict__ hb,
    const float* __restrict__ W1, const float* __restrict__ b1,
    const float* __restrict__ W2, const float* __restrict__ b2,
    float* __restrict__ rTw, float* __restrict__ out){
  __shared__ __align__(16) unsigned short As[16384];
  __shared__ __align__(16) unsigned short Bs[16384];
  __shared__ float zpart[2][128];
  __shared__ float s4[4];
  int i0 = blockIdx.x * 128;
  int tid = threadIdx.x;
  stage_tile(hb + (size_t)i0 * 128, As);
  #pragma unroll
  for (int it = 0; it < 8; ++it){
    int c = tid + it * 256;
    int row = c >> 4, cc = c & 15;
    int src = (row << 4) + (cc ^ (row & 7));
    const float4* g4 = (const float4*)(W1 + src * 8);
    float4 a = g4[0], b = g4[1];
    unsigned short t8[8];
    t8[0] = f2bf(a.x); t8[1] = f2bf(a.y); t8[2] = f2bf(a.z); t8[3] = f2bf(a.w);
    t8[4] = f2bf(b.x); t8[5] = f2bf(b.y); t8[6] = f2bf(b.z); t8[7] = f2bf(b.w);
    *(uint4*)(Bs + c * 8) = *(uint4*)t8;
  }
  asm volatile("s_waitcnt vmcnt(0)" ::: "memory");
  __syncthreads();
  f32x4 acc[4][4];
  mfma_tile(As, Bs, acc);
  int w = tid >> 6, l = tid & 63;
  int wrb = (w >> 1) * 64, wcb = (w & 1) * 64, lo = l & 15, hi = l >> 4;
  float w2v[4], b1v[4];
  #pragma unroll
  for (int n = 0; n < 4; ++n){ int col = wcb + n * 16 + lo; w2v[n] = W2[col]; b1v[n] = b1[col]; }
  #pragma unroll
  for (int m = 0; m < 4; ++m){
    #pragma unroll
    for (int q = 0; q < 4; ++q){
      float p = 0.f;
      #pragma unroll
      for (int n = 0; n < 4; ++n){
        float hv = acc[m][n][q] + b1v[n];
        hv = hv >= 0.f ? hv : 0.2f * hv;   // leaky_relu(0.2)
        p += hv * w2v[n];
      }
      p += __shfl_xor(p, 1); p += __shfl_xor(p, 2);
      p += __shfl_xor(p, 4); p += __shfl_xor(p, 8);
      if (lo == 0) zpart[w & 1][wrb + m * 16 + hi * 4 + q] = p;
    }
  }
  __syncthreads();
  float Tloc = 0.f;
  if (tid < 128){
    float z = zpart[0][tid] + zpart[1][tid] + b2[0];
    float s = 1.f / (1.f + __expf(-z));
    float T = 0.95f * (1.f - s) + 0.05f;
    rTw[i0 + tid] = 1.f / T;
    Tloc = T;
  }
  float v = Tloc;
  #pragma unroll
  for (int o = 32; o; o >>= 1) v += __shfl_xor(v, o);
  if ((tid & 63) == 0) s4[tid >> 6] = v;
  __syncthreads();
  if (tid == 0) atomicAdd(out + OUT_AVG, (s4[0] + s4[1] + s4[2] + s4[3]) * (1.0f / 8192.0f));
}

// ------- phase 3: block-specialized fused kernel (R10, best known) --------------
__global__ __launch_bounds__(256) void k_main(const unsigned short* __restrict__ f1b,
    const unsigned short* __restrict__ f2b, const float* __restrict__ rTw,
    const float* __restrict__ posw, float* __restrict__ out){
  __shared__ __align__(16) unsigned short Buf[16384];   // 32 KB (GEMM role only)
  __shared__ __align__(16) float rS[128];
  int bid = blockIdx.x;
  int tid = threadIdx.x;
  if (bid % 5 == 2){
    // ---------------- GEMM role ----------------
    int g = bid / 5;
    int s = (g & 7) * 64 + (g >> 3);    // XCD-chunked, bijective (512 % 8 == 0)
    int rt = s & 63, ctg = s >> 6;
    int w = tid >> 6, l = tid & 63;
    int wr = (w >> 1) * 64, wc = (w & 1) * 64;
    int lo = l & 15, hi = l >> 4;
    stage_tile(f1b + (size_t)rt * 16384, Buf);
    if (tid < 32)
      __builtin_amdgcn_global_load_lds((as1u32*)(rTw + rt * 128 + tid * 4),
                                       (as3u32*)(rS + tid * 4), 16, 0, 0);
    asm volatile("s_waitcnt vmcnt(0)" ::: "memory");
    __builtin_amdgcn_s_barrier();
    bf16x8 af[4][4];                 // A fragments in registers
    #pragma unroll
    for (int kk = 0; kk < 4; ++kk)
      #pragma unroll
      for (int m = 0; m < 4; ++m){
        int row = wr + m * 16 + lo;
        af[kk][m] = *(const bf16x8*)(Buf + row * 128 + ((kk * 4 + hi) ^ (row & 7)) * 8);
      }
    asm volatile("s_waitcnt lgkmcnt(0)" ::: "memory");
    __builtin_amdgcn_s_barrier();    // Buf free for B staging
    stage_tile(f2b + (size_t)(ctg * 8) * 16384, Buf);
    asm volatile("s_waitcnt vmcnt(0)" ::: "memory");
    __builtin_amdgcn_s_barrier();    // B(0) ready
    float pacc[4][4] = {{0.f,0.f,0.f,0.f},{0.f,0.f,0.f,0.f},{0.f,0.f,0.f,0.f},{0.f,0.f,0.f,0.f}};
    #pragma unroll 1
    for (int c8 = 0; c8 < 8; ++c8){
      int ct = ctg * 8 + c8;
      f32x4 acc[4][4];
      f32x4 zero = {0.f,0.f,0.f,0.f};
      #pragma unroll
      for (int m = 0; m < 4; ++m)
        #pragma unroll
        for (int n = 0; n < 4; ++n) acc[m][n] = zero;
      #pragma unroll
      for (int kk = 0; kk < 4; ++kk){
        bf16x8 bfv[4];
        #pragma unroll
        for (int n = 0; n < 4; ++n){
          int row = wc + n * 16 + lo;
          bfv[n] = *(const bf16x8*)(Buf + row * 128 + ((kk * 4 + hi) ^ (row & 7)) * 8);
        }
        #pragma unroll
        for (int m = 0; m < 4; ++m)
          #pragma unroll
          for (int n = 0; n < 4; ++n)
            acc[m][n] = __builtin_amdgcn_mfma_f32_16x16x32_bf16(af[kk][m], bfv[n], acc[m][n], 0, 0, 0);
      }
      asm volatile("s_waitcnt lgkmcnt(0)" ::: "memory");
      __builtin_amdgcn_s_barrier();        // all waves done reading Buf
      if (c8 < 7) stage_tile(f2b + (size_t)(ct + 1) * 16384, Buf);   // prefetch next
      #pragma unroll
      for (int m = 0; m < 4; ++m)
        #pragma unroll
        for (int q = 0; q < 4; ++q){
          float r = rS[wr + m * 16 + hi * 4 + q];
          pacc[m][q] += __expf(acc[m][0][q] * r) + __expf(acc[m][1][q] * r)
                      + __expf(acc[m][2][q] * r) + __expf(acc[m][3][q] * r);
        }
      if (c8 < 7){
        asm volatile("s_waitcnt vmcnt(0)" ::: "memory");
        __builtin_amdgcn_s_barrier();      // B(c8+1) ready
      }
    }
    #pragma unroll
    for (int m = 0; m < 4; ++m)
      #pragma unroll
      for (int q = 0; q < 4; ++q){
        float p = pacc[m][q];
        p += __shfl_xor(p, 1); p += __shfl_xor(p, 2);
        p += __shfl_xor(p, 4); p += __shfl_xor(p, 8);
        if (lo == 0) atomicAdd(out + OUT_TOT + rt * 128 + wr + m * 16 + hi * 4 + q, p);
      }
  } else {
    // ---------------- writer role ----------------
    int wid = bid - bid / 5 - ((bid % 5) > 2 ? 1 : 0);   // 0..2047, bijective
    int r0 = wid * 4;
    f32x4 p[8];
    #pragma unroll
    for (int c = 0; c < 8; ++c) p[c] = *(const f32x4*)(posw + (c * 256 + tid) * 4);
    float4 rr4 = *(const float4*)(rTw + r0);
    float rr[4] = {rr4.x, rr4.y, rr4.z, rr4.w};
    #pragma unroll
    for (int r = 0; r < 4; ++r){
      float* ob = out + (size_t)(r0 + r) * B_TOT;
      #pragma unroll
      for (int c = 0; c < 8; ++c){
        f32x4 e;
        e.x = __expf(p[c].x * rr[r]); e.y = __expf(p[c].y * rr[r]);
        e.z = __expf(p[c].z * rr[r]); e.w = __expf(p[c].w * rr[r]);
        *(f32x4*)(ob + (c * 256 + tid) * 4) = e;
      }
    }
  }
}

extern "C" void kernel_launch(void* const* d_in, const int* in_sizes, int n_in,
                              void* d_out, int out_size, void* d_ws, size_t ws_size,
                              hipStream_t stream){
  const float* x1 = (const float*)d_in[0];
  const float* x2 = (const float*)d_in[1];
  const int*   i1 = (const int*)d_in[2];
  const int*   i2 = (const int*)d_in[3];
  const float* W1 = (const float*)d_in[4];
  const float* b1 = (const float*)d_in[5];
  const float* W2 = (const float*)d_in[6];
  const float* b2 = (const float*)d_in[7];
  float* out = (float*)d_out;
  char* ws = (char*)d_ws;
  unsigned short* hb   = (unsigned short*)(ws);              // 2 MB
  unsigned short* f1b  = (unsigned short*)(ws + 2097152);    // 2 MB
  unsigned short* f2b  = (unsigned short*)(ws + 4194304);    // 2 MB
  float* posw  = (float*)(ws + 6291456);                     // 32 KB
  float* rTw   = (float*)(ws + 6324224);                     // 32 KB

  // PROBE: k_feat launched 3x (idempotent; re-zeros its accumulators each run).
  // dur - 85.9 = 2*T(feat) + 2*gap.
  hipLaunchKernelGGL(k_feat, dim3(2048), dim3(256), 0, stream, x1, x2, i1, i2, f1b, f2b, hb, posw, out);
  hipLaunchKernelGGL(k_feat, dim3(2048), dim3(256), 0, stream, x1, x2, i1, i2, f1b, f2b, hb, posw, out);
  hipLaunchKernelGGL(k_feat, dim3(2048), dim3(256), 0, stream, x1, x2, i1, i2, f1b, f2b, hb, posw, out);
  hipLaunchKernelGGL(k_lin,  dim3(64),   dim3(256), 0, stream, hb, W1, b1, W2, b2, rTw, out);
  hipLaunchKernelGGL(k_main, dim3(2560), dim3(256), 0, stream, f1b, f2b, rTw, posw, out);
}

// Round 14
// 94.959 us; speedup vs baseline: 1.7585x; 1.0000x over previous
//
#include <hip/hip_runtime.h>
#include <stdint.h>

typedef __bf16 bf16x8 __attribute__((ext_vector_type(8)));
typedef float f32x4 __attribute__((ext_vector_type(4)));
typedef __attribute__((address_space(3))) uint32_t as3u32;
typedef const __attribute__((address_space(1))) uint32_t as1u32;

#define B_TOT 8192
#define DD 128
#define OUT_TOT 67108864UL
#define OUT_AVG 67117056UL

__device__ inline unsigned short f2bf(float x){
  union { float f; uint32_t u; } v; v.f = x;
  return (unsigned short)((v.u + 0x7fffu + ((v.u >> 16) & 1u)) >> 16);
}
__device__ inline float bf2f(unsigned short u){
  union { uint32_t u; float f; } v; v.u = (uint32_t)u << 16; return v.f;
}

// ------- phase 1: gather + normalize + h + pos; one wave per sample ------------
__global__ __launch_bounds__(256) void k_feat(const float* __restrict__ x1,
    const float* __restrict__ x2, const int* __restrict__ i1a, const int* __restrict__ i2a,
    unsigned short* __restrict__ f1b, unsigned short* __restrict__ f2b,
    unsigned short* __restrict__ hb, float* __restrict__ posw, float* __restrict__ out){
  int tid = threadIdx.x;
  int gid = blockIdx.x * 256 + tid;
  if (gid <= 8192) out[OUT_TOT + gid] = 0.f;   // zero tot accum + avg slot
  int w = tid >> 6, l = tid & 63;
  int b = blockIdx.x * 4 + w;                  // grid 2048 -> b 0..8191
  const float2* r1 = (const float2*)(x1 + (size_t)i1a[b] * DD);
  const float2* r2 = (const float2*)(x2 + (size_t)i2a[b] * DD);
  float2 v1 = r1[l], v2 = r2[l];
  float s1 = v1.x * v1.x + v1.y * v1.y;
  float s2 = v2.x * v2.x + v2.y * v2.y;
  #pragma unroll
  for (int o = 32; o; o >>= 1){ s1 += __shfl_xor(s1, o); s2 += __shfl_xor(s2, o); }
  float inv1 = 1.f / fmaxf(sqrtf(s1), 1e-12f);
  float inv2 = 1.f / fmaxf(sqrtf(s2), 1e-12f);
  float f1x = v1.x * inv1, f1y = v1.y * inv1;
  float f2x = v2.x * inv2, f2y = v2.y * inv2;
  float hx = f1x * f2x, hy = f1y * f2y;
  float ps = hx + hy;
  #pragma unroll
  for (int o = 32; o; o >>= 1) ps += __shfl_xor(ps, o);
  unsigned int u1 = (unsigned int)f2bf(f1x) | ((unsigned int)f2bf(f1y) << 16);
  unsigned int u2 = (unsigned int)f2bf(f2x) | ((unsigned int)f2bf(f2y) << 16);
  unsigned int uh = (unsigned int)f2bf(hx)  | ((unsigned int)f2bf(hy)  << 16);
  ((unsigned int*)f1b)[b * 64 + l] = u1;
  ((unsigned int*)f2b)[b * 64 + l] = u2;
  ((unsigned int*)hb)[b * 64 + l]  = uh;
  if (l == 0) posw[b] = ps;
}

// ---------------- shared staging (128x128 bf16 tile, XOR-swizzled) ----------------
__device__ inline void stage_tile(const unsigned short* g, unsigned short* s){
  int tid = threadIdx.x;
  #pragma unroll
  for (int it = 0; it < 8; ++it){
    int c = tid + it * 256;          // 2048 chunks of 16B
    int row = c >> 4, cc = c & 15;
    int src = (row << 4) + (cc ^ (row & 7));
    __builtin_amdgcn_global_load_lds((as1u32*)(g + src * 8),
                                     (as3u32*)(s + c * 8), 16, 0, 0);
  }
}

// ------- phase 2 v2: lin1+leaky+lin2+sigmoid -> rT, temp-mean. 512 blocks -------
// Block = 16 rows. W1 staged f32 in LDS (64 KB); pure-VALU matvec, per-lane
// k-stagger puts b128 LDS reads at the 8-cyc bank floor. 2 blocks/CU, one
// generation across the chip (512 = 256 CU x 2).
__global__ __launch_bounds__(256) void k_lin(const unsigned short* __restrict__ hb,
    const float* __restrict__ W1, const float* __restrict__ b1,
    const float* __restrict__ W2, const float* __restrict__ b2,
    float* __restrict__ rTw, float* __restrict__ out){
  __shared__ __align__(16) float W1S[16384];        // 64 KB
  __shared__ __align__(16) unsigned short hS[2048]; // 4 KB
  __shared__ float s4[4];
  int tid = threadIdx.x;
  int i0 = blockIdx.x * 16;
  #pragma unroll
  for (int it = 0; it < 16; ++it){
    int c = tid + it * 256;
    __builtin_amdgcn_global_load_lds((as1u32*)(W1 + c * 4), (as3u32*)(W1S + c * 4), 16, 0, 0);
  }
  __builtin_amdgcn_global_load_lds((as1u32*)(hb + (size_t)i0 * 128 + tid * 8),
                                   (as3u32*)(hS + tid * 8), 16, 0, 0);
  asm volatile("s_waitcnt vmcnt(0)" ::: "memory");
  __syncthreads();
  int l = tid & 63;
  int r = tid >> 4;            // row 0..15
  int j0 = (tid & 15) * 8;     // 8 output cols per thread
  float acc[8] = {0.f,0.f,0.f,0.f,0.f,0.f,0.f,0.f};
  int kq0 = ((l & 15) * 2 + (l >> 4)) & 31;   // bank stagger
  #pragma unroll 4
  for (int i = 0; i < 32; ++i){
    int kq = (kq0 + i) & 31;
    ushort4 hu = *(const ushort4*)(hS + r * 128 + kq * 4);
    float h0 = bf2f(hu.x), h1 = bf2f(hu.y), h2 = bf2f(hu.z), h3 = bf2f(hu.w);
    #pragma unroll
    for (int jj = 0; jj < 8; ++jj){
      f32x4 wq = *(const f32x4*)(W1S + (j0 + jj) * 128 + kq * 4);
      acc[jj] += h0 * wq.x + h1 * wq.y + h2 * wq.z + h3 * wq.w;
    }
  }
  float p = 0.f;
  #pragma unroll
  for (int jj = 0; jj < 8; ++jj){
    int j = j0 + jj;
    float z = acc[jj] + b1[j];
    z = z >= 0.f ? z : 0.2f * z;     // leaky_relu(0.2)
    p += z * W2[j];
  }
  p += __shfl_xor(p, 1); p += __shfl_xor(p, 2);
  p += __shfl_xor(p, 4); p += __shfl_xor(p, 8);
  float T = 0.f;
  if ((tid & 15) == 0){
    float z2 = p + b2[0];
    float s = 1.f / (1.f + __expf(-z2));
    T = 0.95f * (1.f - s) + 0.05f;
    rTw[i0 + r] = 1.f / T;
  }
  float v = T;                        // nonzero only at (l&15)==0
  v += __shfl_xor(v, 16); v += __shfl_xor(v, 32);
  if (l == 0) s4[tid >> 6] = v;
  __syncthreads();
  if (tid == 0) atomicAdd(out + OUT_AVG, (s4[0]+s4[1]+s4[2]+s4[3]) * (1.f/8192.f));
}

// ------- phase 3 v2: tot GEMM, 1024 blocks (rt x 4-tile col-group) --------------
__global__ __launch_bounds__(256, 2) void k_tot(const unsigned short* __restrict__ f1b,
    const unsigned short* __restrict__ f2b, const float* __restrict__ rTw,
    float* __restrict__ out){
  __shared__ __align__(16) unsigned short Buf[16384];   // 32 KB
  __shared__ __align__(16) float rS[128];
  int g = blockIdx.x;
  int s = (g & 7) * 128 + (g >> 3);     // XCD-chunked, bijective (1024 % 8 == 0)
  int rt = s & 63, cg = s >> 6;         // cg 0..15 (4 B-tiles each)
  int tid = threadIdx.x, w = tid >> 6, l = tid & 63;
  int wr = (w >> 1) * 64, wc = (w & 1) * 64;
  int lo = l & 15, hi = l >> 4;
  stage_tile(f1b + (size_t)rt * 16384, Buf);
  if (tid < 32)
    __builtin_amdgcn_global_load_lds((as1u32*)(rTw + rt * 128 + tid * 4),
                                     (as3u32*)(rS + tid * 4), 16, 0, 0);
  asm volatile("s_waitcnt vmcnt(0)" ::: "memory");
  __builtin_amdgcn_s_barrier();
  bf16x8 af[4][4];                 // A fragments in registers
  #pragma unroll
  for (int kk = 0; kk < 4; ++kk)
    #pragma unroll
    for (int m = 0; m < 4; ++m){
      int row = wr + m * 16 + lo;
      af[kk][m] = *(const bf16x8*)(Buf + row * 128 + ((kk * 4 + hi) ^ (row & 7)) * 8);
    }
  asm volatile("s_waitcnt lgkmcnt(0)" ::: "memory");
  __builtin_amdgcn_s_barrier();    // Buf free for B staging
  stage_tile(f2b + (size_t)(cg * 4) * 16384, Buf);
  asm volatile("s_waitcnt vmcnt(0)" ::: "memory");
  __builtin_amdgcn_s_barrier();    // B(0) ready
  float pacc[4][4] = {{0.f,0.f,0.f,0.f},{0.f,0.f,0.f,0.f},{0.f,0.f,0.f,0.f},{0.f,0.f,0.f,0.f}};
  #pragma unroll 1
  for (int c4 = 0; c4 < 4; ++c4){
    int ct = cg * 4 + c4;
    f32x4 acc[4][4];
    f32x4 zero = {0.f,0.f,0.f,0.f};
    #pragma unroll
    for (int m = 0; m < 4; ++m)
      #pragma unroll
      for (int n = 0; n < 4; ++n) acc[m][n] = zero;
    #pragma unroll
    for (int kk = 0; kk < 4; ++kk){
      bf16x8 bfv[4];
      #pragma unroll
      for (int n = 0; n < 4; ++n){
        int row = wc + n * 16 + lo;
        bfv[n] = *(const bf16x8*)(Buf + row * 128 + ((kk * 4 + hi) ^ (row & 7)) * 8);
      }
      #pragma unroll
      for (int m = 0; m < 4; ++m)
        #pragma unroll
        for (int n = 0; n < 4; ++n)
          acc[m][n] = __builtin_amdgcn_mfma_f32_16x16x32_bf16(af[kk][m], bfv[n], acc[m][n], 0, 0, 0);
    }
    asm volatile("s_waitcnt lgkmcnt(0)" ::: "memory");
    __builtin_amdgcn_s_barrier();        // all waves done reading Buf
    if (c4 < 3) stage_tile(f2b + (size_t)(ct + 1) * 16384, Buf);   // prefetch next
    #pragma unroll
    for (int m = 0; m < 4; ++m)
      #pragma unroll
      for (int q = 0; q < 4; ++q){
        float r = rS[wr + m * 16 + hi * 4 + q];
        pacc[m][q] += __expf(acc[m][0][q] * r) + __expf(acc[m][1][q] * r)
                    + __expf(acc[m][2][q] * r) + __expf(acc[m][3][q] * r);
      }
    if (c4 < 3){
      asm volatile("s_waitcnt vmcnt(0)" ::: "memory");
      __builtin_amdgcn_s_barrier();      // B(c4+1) ready
    }
  }
  #pragma unroll
  for (int m = 0; m < 4; ++m)
    #pragma unroll
    for (int q = 0; q < 4; ++q){
      float p = pacc[m][q];
      p += __shfl_xor(p, 1); p += __shfl_xor(p, 2);
      p += __shfl_xor(p, 4); p += __shfl_xor(p, 8);
      if (lo == 0) atomicAdd(out + OUT_TOT + rt * 128 + wr + m * 16 + hi * 4 + q, p);
    }
}

// ------- phase 4: pos_rating writer (R9/R12-proven 39.5 us shape) ---------------
__global__ __launch_bounds__(256) void k_pr(const float* __restrict__ posw,
    const float* __restrict__ rTw, float* __restrict__ out){
  int tid = threadIdx.x;
  int r0 = blockIdx.x * 4;
  f32x4 p[8];
  #pragma unroll
  for (int c = 0; c < 8; ++c) p[c] = *(const f32x4*)(posw + (c * 256 + tid) * 4);
  float4 rr4 = *(const float4*)(rTw + r0);
  float rr[4] = {rr4.x, rr4.y, rr4.z, rr4.w};
  #pragma unroll
  for (int r = 0; r < 4; ++r){
    float* ob = out + (size_t)(r0 + r) * B_TOT;
    #pragma unroll
    for (int c = 0; c < 8; ++c){
      f32x4 e;
      e.x = __expf(p[c].x * rr[r]); e.y = __expf(p[c].y * rr[r]);
      e.z = __expf(p[c].z * rr[r]); e.w = __expf(p[c].w * rr[r]);
      *(f32x4*)(ob + (c * 256 + tid) * 4) = e;
    }
  }
}

extern "C" void kernel_launch(void* const* d_in, const int* in_sizes, int n_in,
                              void* d_out, int out_size, void* d_ws, size_t ws_size,
                              hipStream_t stream){
  const float* x1 = (const float*)d_in[0];
  const float* x2 = (const float*)d_in[1];
  const int*   i1 = (const int*)d_in[2];
  const int*   i2 = (const int*)d_in[3];
  const float* W1 = (const float*)d_in[4];
  const float* b1 = (const float*)d_in[5];
  const float* W2 = (const float*)d_in[6];
  const float* b2 = (const float*)d_in[7];
  float* out = (float*)d_out;
  char* ws = (char*)d_ws;
  unsigned short* hb   = (unsigned short*)(ws);              // 2 MB
  unsigned short* f1b  = (unsigned short*)(ws + 2097152);    // 2 MB
  unsigned short* f2b  = (unsigned short*)(ws + 4194304);    // 2 MB
  float* posw  = (float*)(ws + 6291456);                     // 32 KB
  float* rTw   = (float*)(ws + 6324224);                     // 32 KB

  hipLaunchKernelGGL(k_feat, dim3(2048), dim3(256), 0, stream, x1, x2, i1, i2, f1b, f2b, hb, posw, out);
  hipLaunchKernelGGL(k_lin,  dim3(512),  dim3(256), 0, stream, hb, W1, b1, W2, b2, rTw, out);
  hipLaunchKernelGGL(k_tot,  dim3(1024), dim3(256), 0, stream, f1b, f2b, rTw, out);
  hipLaunchKernelGGL(k_pr,   dim3(2048), dim3(256), 0, stream, posw, rTw, out);
}

// Round 15
// 87.684 us; speedup vs baseline: 1.9044x; 1.0830x over previous
//
#include <hip/hip_runtime.h>
#include <stdint.h>

typedef __bf16 bf16x8 __attribute__((ext_vector_type(8)));
typedef float f32x4 __attribute__((ext_vector_type(4)));
typedef __attribute__((address_space(3))) uint32_t as3u32;
typedef const __attribute__((address_space(1))) uint32_t as1u32;

#define B_TOT 8192
#define DD 128
#define OUT_TOT 67108864UL
#define OUT_AVG 67117056UL

__device__ inline unsigned short f2bf(float x){
  union { float f; uint32_t u; } v; v.f = x;
  return (unsigned short)((v.u + 0x7fffu + ((v.u >> 16) & 1u)) >> 16);
}

// ------- phase 1: gather + normalize + h + pos; one wave per sample ------------
__global__ __launch_bounds__(256) void k_feat(const float* __restrict__ x1,
    const float* __restrict__ x2, const int* __restrict__ i1a, const int* __restrict__ i2a,
    unsigned short* __restrict__ f1b, unsigned short* __restrict__ f2b,
    unsigned short* __restrict__ hb, float* __restrict__ posw, float* __restrict__ out){
  int tid = threadIdx.x;
  int gid = blockIdx.x * 256 + tid;
  if (gid <= 8192) out[OUT_TOT + gid] = 0.f;   // zero tot accum + avg slot
  int w = tid >> 6, l = tid & 63;
  int b = blockIdx.x * 4 + w;                  // grid 2048 -> b 0..8191
  const float2* r1 = (const float2*)(x1 + (size_t)i1a[b] * DD);
  const float2* r2 = (const float2*)(x2 + (size_t)i2a[b] * DD);
  float2 v1 = r1[l], v2 = r2[l];
  float s1 = v1.x * v1.x + v1.y * v1.y;
  float s2 = v2.x * v2.x + v2.y * v2.y;
  #pragma unroll
  for (int o = 32; o; o >>= 1){ s1 += __shfl_xor(s1, o); s2 += __shfl_xor(s2, o); }
  float inv1 = 1.f / fmaxf(sqrtf(s1), 1e-12f);
  float inv2 = 1.f / fmaxf(sqrtf(s2), 1e-12f);
  float f1x = v1.x * inv1, f1y = v1.y * inv1;
  float f2x = v2.x * inv2, f2y = v2.y * inv2;
  float hx = f1x * f2x, hy = f1y * f2y;
  float ps = hx + hy;
  #pragma unroll
  for (int o = 32; o; o >>= 1) ps += __shfl_xor(ps, o);
  unsigned int u1 = (unsigned int)f2bf(f1x) | ((unsigned int)f2bf(f1y) << 16);
  unsigned int u2 = (unsigned int)f2bf(f2x) | ((unsigned int)f2bf(f2y) << 16);
  unsigned int uh = (unsigned int)f2bf(hx)  | ((unsigned int)f2bf(hy)  << 16);
  ((unsigned int*)f1b)[b * 64 + l] = u1;
  ((unsigned int*)f2b)[b * 64 + l] = u2;
  ((unsigned int*)hb)[b * 64 + l]  = uh;
  if (l == 0) posw[b] = ps;
}

// ------- staging helpers (XOR-swizzled, rule #21: pre-swizzled global src) ------
__device__ inline void stage_tile(const unsigned short* g, unsigned short* s){
  int tid = threadIdx.x;
  #pragma unroll
  for (int it = 0; it < 8; ++it){
    int c = tid + it * 256;          // 2048 chunks of 16B (128 rows x 16 chunks)
    int row = c >> 4, cc = c & 15;
    int src = (row << 4) + (cc ^ (row & 7));
    __builtin_amdgcn_global_load_lds((as1u32*)(g + src * 8),
                                     (as3u32*)(s + c * 8), 16, 0, 0);
  }
}
// 64-row (16 KB) variant for B sub-tiles
__device__ inline void stage_tile64(const unsigned short* g, unsigned short* s){
  int tid = threadIdx.x;
  #pragma unroll
  for (int it = 0; it < 4; ++it){
    int c = tid + it * 256;          // 1024 chunks (64 rows x 16 chunks)
    int row = c >> 4, cc = c & 15;
    int src = (row << 4) + (cc ^ (row & 7));
    __builtin_amdgcn_global_load_lds((as1u32*)(g + src * 8),
                                     (as3u32*)(s + c * 8), 16, 0, 0);
  }
}

// A-frag: row = lane&15, k = 8*(lane>>4)+e. C/D: col = lane&15, row=(lane>>4)*4+reg.
__device__ inline void mfma_tile(const unsigned short* As, const unsigned short* Bs,
                                 f32x4 acc[4][4]){
  int tid = threadIdx.x;
  int w = tid >> 6, l = tid & 63;
  int wr = (w >> 1) * 64, wc = (w & 1) * 64;
  int lo = l & 15, hi = l >> 4;
  f32x4 zero = {0.f, 0.f, 0.f, 0.f};
  #pragma unroll
  for (int m = 0; m < 4; ++m)
    #pragma unroll
    for (int n = 0; n < 4; ++n) acc[m][n] = zero;
  #pragma unroll
  for (int kk = 0; kk < 4; ++kk){
    bf16x8 af[4], bfv[4];
    #pragma unroll
    for (int m = 0; m < 4; ++m){
      int row = wr + m * 16 + lo;
      af[m] = *(const bf16x8*)(As + row * 128 + ((kk * 4 + hi) ^ (row & 7)) * 8);
    }
    #pragma unroll
    for (int n = 0; n < 4; ++n){
      int row = wc + n * 16 + lo;
      bfv[n] = *(const bf16x8*)(Bs + row * 128 + ((kk * 4 + hi) ^ (row & 7)) * 8);
    }
    #pragma unroll
    for (int m = 0; m < 4; ++m)
      #pragma unroll
      for (int n = 0; n < 4; ++n)
        acc[m][n] = __builtin_amdgcn_mfma_f32_16x16x32_bf16(af[m], bfv[n], acc[m][n], 0, 0, 0);
  }
}

// ---------------- phase 2: lin1 + leaky + lin2 + sigmoid -> rT, temp-mean -------
__global__ __launch_bounds__(256) void k_lin(const unsigned short* __restrict__ hb,
    const float* __restrict__ W1, const float* __restrict__ b1,
    const float* __restrict__ W2, const float* __restrict__ b2,
    float* __restrict__ rTw, float* __restrict__ out){
  __shared__ __align__(16) unsigned short As[16384];
  __shared__ __align__(16) unsigned short Bs[16384];
  __shared__ float zpart[2][128];
  __shared__ float s4[4];
  int i0 = blockIdx.x * 128;
  int tid = threadIdx.x;
  stage_tile(hb + (size_t)i0 * 128, As);
  #pragma unroll
  for (int it = 0; it < 8; ++it){
    int c = tid + it * 256;
    int row = c >> 4, cc = c & 15;
    int src = (row << 4) + (cc ^ (row & 7));
    const float4* g4 = (const float4*)(W1 + src * 8);
    float4 a = g4[0], b = g4[1];
    unsigned short t8[8];
    t8[0] = f2bf(a.x); t8[1] = f2bf(a.y); t8[2] = f2bf(a.z); t8[3] = f2bf(a.w);
    t8[4] = f2bf(b.x); t8[5] = f2bf(b.y); t8[6] = f2bf(b.z); t8[7] = f2bf(b.w);
    *(uint4*)(Bs + c * 8) = *(uint4*)t8;
  }
  asm volatile("s_waitcnt vmcnt(0)" ::: "memory");
  __syncthreads();
  f32x4 acc[4][4];
  mfma_tile(As, Bs, acc);
  int w = tid >> 6, l = tid & 63;
  int wrb = (w >> 1) * 64, wcb = (w & 1) * 64, lo = l & 15, hi = l >> 4;
  float w2v[4], b1v[4];
  #pragma unroll
  for (int n = 0; n < 4; ++n){ int col = wcb + n * 16 + lo; w2v[n] = W2[col]; b1v[n] = b1[col]; }
  #pragma unroll
  for (int m = 0; m < 4; ++m){
    #pragma unroll
    for (int q = 0; q < 4; ++q){
      float p = 0.f;
      #pragma unroll
      for (int n = 0; n < 4; ++n){
        float hv = acc[m][n][q] + b1v[n];
        hv = hv >= 0.f ? hv : 0.2f * hv;   // leaky_relu(0.2)
        p += hv * w2v[n];
      }
      p += __shfl_xor(p, 1); p += __shfl_xor(p, 2);
      p += __shfl_xor(p, 4); p += __shfl_xor(p, 8);
      if (lo == 0) zpart[w & 1][wrb + m * 16 + hi * 4 + q] = p;
    }
  }
  __syncthreads();
  float Tloc = 0.f;
  if (tid < 128){
    float z = zpart[0][tid] + zpart[1][tid] + b2[0];
    float s = 1.f / (1.f + __expf(-z));
    float T = 0.95f * (1.f - s) + 0.05f;
    rTw[i0 + tid] = 1.f / T;
    Tloc = T;
  }
  float v = Tloc;
  #pragma unroll
  for (int o = 32; o; o >>= 1) v += __shfl_xor(v, o);
  if ((tid & 63) == 0) s4[tid >> 6] = v;
  __syncthreads();
  if (tid == 0) atomicAdd(out + OUT_AVG, (s4[0] + s4[1] + s4[2] + s4[3]) * (1.0f / 8192.0f));
}

// ------- phase 3 v3: tot GEMM with counted-vmcnt double-buffered B pipeline -----
// No stores in the loop -> vmcnt counts are exact. A in regs; B in 2 x 16 KB
// buffers, depth-2 prefetch, vmcnt(4) per iter (last iter vmcnt(0)).
__global__ __launch_bounds__(256, 2) void k_tot(const unsigned short* __restrict__ f1b,
    const unsigned short* __restrict__ f2b, const float* __restrict__ rTw,
    float* __restrict__ out){
  __shared__ __align__(16) unsigned short Abuf[16384];   // 32 KB
  __shared__ __align__(16) unsigned short Bbuf0[8192];   // 16 KB
  __shared__ __align__(16) unsigned short Bbuf1[8192];   // 16 KB
  __shared__ __align__(16) float rS[128];
  int s = (blockIdx.x & 7) * 64 + (blockIdx.x >> 3);     // XCD-chunked, bijective
  int rt = s & 63, ctg = s >> 6;
  int tid = threadIdx.x, w = tid >> 6, l = tid & 63;
  int wr = (w >> 1) * 64, wc = (w & 1) * 32;   // 2x2 wave grid over 128x64
  int lo = l & 15, hi = l >> 4;
  const unsigned short* Bg = f2b + (size_t)(ctg * 1024) * 128;  // 1024 cols
  // prologue: A + rT + B sub-tiles 0,1
  stage_tile(f1b + (size_t)rt * 16384, Abuf);
  if (tid < 32)
    __builtin_amdgcn_global_load_lds((as1u32*)(rTw + rt * 128 + tid * 4),
                                     (as3u32*)(rS + tid * 4), 16, 0, 0);
  stage_tile64(Bg, Bbuf0);
  stage_tile64(Bg + 64 * 128, Bbuf1);
  asm volatile("s_waitcnt vmcnt(0)" ::: "memory");
  __builtin_amdgcn_s_barrier();
  bf16x8 af[4][4];                 // [kk][m] A fragments (64 VGPR)
  #pragma unroll
  for (int kk = 0; kk < 4; ++kk)
    #pragma unroll
    for (int m = 0; m < 4; ++m){
      int row = wr + m * 16 + lo;
      af[kk][m] = *(const bf16x8*)(Abuf + row * 128 + ((kk * 4 + hi) ^ (row & 7)) * 8);
    }
  float pacc[4][4] = {{0.f,0.f,0.f,0.f},{0.f,0.f,0.f,0.f},{0.f,0.f,0.f,0.f},{0.f,0.f,0.f,0.f}};
  unsigned short* ba = Bbuf0;      // current
  unsigned short* bb = Bbuf1;      // next
  #pragma unroll 1
  for (int i = 0; i < 16; ++i){
    if (i < 15) asm volatile("s_waitcnt vmcnt(4)" ::: "memory");
    else        asm volatile("s_waitcnt vmcnt(0)" ::: "memory");
    __builtin_amdgcn_s_barrier();            // buffer 'ba' ready for all waves
    f32x4 acc[4][2];
    f32x4 zero = {0.f,0.f,0.f,0.f};
    #pragma unroll
    for (int m = 0; m < 4; ++m){ acc[m][0] = zero; acc[m][1] = zero; }
    #pragma unroll
    for (int kk = 0; kk < 4; ++kk){
      bf16x8 bfv[2];
      #pragma unroll
      for (int n = 0; n < 2; ++n){
        int row = wc + n * 16 + lo;
        bfv[n] = *(const bf16x8*)(ba + row * 128 + ((kk * 4 + hi) ^ (row & 7)) * 8);
      }
      #pragma unroll
      for (int m = 0; m < 4; ++m){
        acc[m][0] = __builtin_amdgcn_mfma_f32_16x16x32_bf16(af[kk][m], bfv[0], acc[m][0], 0, 0, 0);
        acc[m][1] = __builtin_amdgcn_mfma_f32_16x16x32_bf16(af[kk][m], bfv[1], acc[m][1], 0, 0, 0);
      }
    }
    asm volatile("s_waitcnt lgkmcnt(0)" ::: "memory");
    __builtin_amdgcn_s_barrier();            // all waves done reading 'ba'
    if (i < 14) stage_tile64(Bg + (size_t)(i + 2) * 64 * 128, ba);  // depth-2 prefetch
    // exp accumulation for this sub-tile (regs/LDS only, overlaps the loads)
    #pragma unroll
    for (int m = 0; m < 4; ++m)
      #pragma unroll
      for (int q = 0; q < 4; ++q){
        float r = rS[wr + m * 16 + hi * 4 + q];
        pacc[m][q] += __expf(acc[m][0][q] * r) + __expf(acc[m][1][q] * r);
      }
    unsigned short* t = ba; ba = bb; bb = t;
  }
  // tot partials: reduce across the 16 col-lanes, one atomic set per block
  #pragma unroll
  for (int m = 0; m < 4; ++m)
    #pragma unroll
    for (int q = 0; q < 4; ++q){
      float p = pacc[m][q];
      p += __shfl_xor(p, 1); p += __shfl_xor(p, 2);
      p += __shfl_xor(p, 4); p += __shfl_xor(p, 8);
      if (lo == 0) atomicAdd(out + OUT_TOT + rt * 128 + wr + m * 16 + hi * 4 + q, p);
    }
}

// ------- phase 4: pos_rating writer (R12-measured ~40 us, write-roofline) -------
__global__ __launch_bounds__(256) void k_pr(const float* __restrict__ posw,
    const float* __restrict__ rTw, float* __restrict__ out){
  int tid = threadIdx.x;
  int r0 = blockIdx.x * 4;
  f32x4 p[8];
  #pragma unroll
  for (int c = 0; c < 8; ++c) p[c] = *(const f32x4*)(posw + (c * 256 + tid) * 4);
  float4 rr4 = *(const float4*)(rTw + r0);
  float rr[4] = {rr4.x, rr4.y, rr4.z, rr4.w};
  #pragma unroll
  for (int r = 0; r < 4; ++r){
    float* ob = out + (size_t)(r0 + r) * B_TOT;
    #pragma unroll
    for (int c = 0; c < 8; ++c){
      f32x4 e;
      e.x = __expf(p[c].x * rr[r]); e.y = __expf(p[c].y * rr[r]);
      e.z = __expf(p[c].z * rr[r]); e.w = __expf(p[c].w * rr[r]);
      *(f32x4*)(ob + (c * 256 + tid) * 4) = e;
    }
  }
}

extern "C" void kernel_launch(void* const* d_in, const int* in_sizes, int n_in,
                              void* d_out, int out_size, void* d_ws, size_t ws_size,
                              hipStream_t stream){
  const float* x1 = (const float*)d_in[0];
  const float* x2 = (const float*)d_in[1];
  const int*   i1 = (const int*)d_in[2];
  const int*   i2 = (const int*)d_in[3];
  const float* W1 = (const float*)d_in[4];
  const float* b1 = (const float*)d_in[5];
  const float* W2 = (const float*)d_in[6];
  const float* b2 = (const float*)d_in[7];
  float* out = (float*)d_out;
  char* ws = (char*)d_ws;
  unsigned short* hb   = (unsigned short*)(ws);              // 2 MB
  unsigned short* f1b  = (unsigned short*)(ws + 2097152);    // 2 MB
  unsigned short* f2b  = (unsigned short*)(ws + 4194304);    // 2 MB
  float* posw  = (float*)(ws + 6291456);                     // 32 KB
  float* rTw   = (float*)(ws + 6324224);                     // 32 KB

  hipLaunchKernelGGL(k_feat, dim3(2048), dim3(256), 0, stream, x1, x2, i1, i2, f1b, f2b, hb, posw, out);
  hipLaunchKernelGGL(k_lin,  dim3(64),   dim3(256), 0, stream, hb, W1, b1, W2, b2, rTw, out);
  hipLaunchKernelGGL(k_tot,  dim3(512),  dim3(256), 0, stream, f1b, f2b, rTw, out);
  hipLaunchKernelGGL(k_pr,   dim3(2048), dim3(256), 0, stream, posw, rTw, out);
}